// Round 3
// baseline (1222.659 us; speedup 1.0000x reference)
//
#include <hip/hip_runtime.h>

#define NN 40000      // nodes
#define NE 640000     // edges
#define DD 128        // feature dim
#define NG 64         // graphs

typedef float vf4 __attribute__((ext_vector_type(4)));

// ---------------------------------------------------------------------------
// CSR build (once per launch; edge_index constant across layers)
// ---------------------------------------------------------------------------
__global__ __launch_bounds__(256) void hist_k(const int* __restrict__ dst,
                                              int* __restrict__ cnt)
{
    int e = blockIdx.x * 256 + threadIdx.x;
    if (e < NE) atomicAdd(&cnt[dst[e]], 1);
}

// 3-phase scan: local sums (40/thread) -> one 1024 ladder -> local writeout
__global__ __launch_bounds__(1024) void scan_k(const int* __restrict__ cnt,
                                               int* __restrict__ row_ptr,
                                               int* __restrict__ cursor)
{
    __shared__ int sm[1024];
    int t = threadIdx.x;
    int base = t * 40;                       // 1024*40 = 40960 >= NN
    int s = 0;
#pragma unroll 8
    for (int i = 0; i < 40; ++i) {
        int idx = base + i;
        if (idx < NN) s += cnt[idx];
    }
    sm[t] = s;
    __syncthreads();
    for (int off = 1; off < 1024; off <<= 1) {
        int x = (t >= off) ? sm[t - off] : 0;
        __syncthreads();
        sm[t] += x;
        __syncthreads();
    }
    int run = sm[t] - s;                     // exclusive prefix
#pragma unroll 8
    for (int i = 0; i < 40; ++i) {
        int idx = base + i;
        if (idx < NN) {
            row_ptr[idx] = run;
            cursor[idx] = run;
            run += cnt[idx];
        }
    }
    if (t == 1023) row_ptr[NN] = run;        // == NE
}

__global__ __launch_bounds__(256) void fill_k(const int* __restrict__ src,
                                              const int* __restrict__ dst,
                                              int* __restrict__ cursor,
                                              int2* __restrict__ elist)
{
    int e = blockIdx.x * 256 + threadIdx.x;
    if (e < NE) {
        int d = dst[e];
        int pos = atomicAdd(&cursor[d], 1);
        elist[pos] = make_int2(src[e], e);
    }
}

// ---------------------------------------------------------------------------
// Atomic-free aggregation: 32 lanes per dst node, 2-edge unroll (4 loads in
// flight per group).  agg[n] = sum_e relu(h[src_e] + ea[eid_e]).
// ---------------------------------------------------------------------------
__global__ __launch_bounds__(256) void gather_k(
    const float* __restrict__ h, const float* __restrict__ ea,
    const int* __restrict__ row_ptr, const int2* __restrict__ elist,
    float* __restrict__ agg)
{
    int grp = blockIdx.x * 8 + (threadIdx.x >> 5);   // node id
    int lane = threadIdx.x & 31;
    if (grp >= NN) return;
    int beg = row_ptr[grp], end = row_ptr[grp + 1];

    float4 acc0 = make_float4(0.f, 0.f, 0.f, 0.f);
    float4 acc1 = make_float4(0.f, 0.f, 0.f, 0.f);
    int e = beg;
    for (; e + 2 <= end; e += 2) {
        int2 p0 = elist[e];
        int2 p1 = elist[e + 1];
        const float4 x0 = *(const float4*)(h + (size_t)p0.x * DD + lane * 4);
        vf4 e0 = __builtin_nontemporal_load(
            (const vf4*)(ea + (size_t)p0.y * DD + lane * 4));
        const float4 x1 = *(const float4*)(h + (size_t)p1.x * DD + lane * 4);
        vf4 e1 = __builtin_nontemporal_load(
            (const vf4*)(ea + (size_t)p1.y * DD + lane * 4));
        acc0.x += fmaxf(x0.x + e0.x, 0.f);
        acc0.y += fmaxf(x0.y + e0.y, 0.f);
        acc0.z += fmaxf(x0.z + e0.z, 0.f);
        acc0.w += fmaxf(x0.w + e0.w, 0.f);
        acc1.x += fmaxf(x1.x + e1.x, 0.f);
        acc1.y += fmaxf(x1.y + e1.y, 0.f);
        acc1.z += fmaxf(x1.z + e1.z, 0.f);
        acc1.w += fmaxf(x1.w + e1.w, 0.f);
    }
    if (e < end) {
        int2 p0 = elist[e];
        const float4 x0 = *(const float4*)(h + (size_t)p0.x * DD + lane * 4);
        vf4 e0 = __builtin_nontemporal_load(
            (const vf4*)(ea + (size_t)p0.y * DD + lane * 4));
        acc0.x += fmaxf(x0.x + e0.x, 0.f);
        acc0.y += fmaxf(x0.y + e0.y, 0.f);
        acc0.z += fmaxf(x0.z + e0.z, 0.f);
        acc0.w += fmaxf(x0.w + e0.w, 0.f);
    }
    float4 outv;
    outv.x = acc0.x + acc1.x;
    outv.y = acc0.y + acc1.y;
    outv.z = acc0.z + acc1.z;
    outv.w = acc0.w + acc1.w;
    *(float4*)(agg + (size_t)grp * DD + lane * 4) = outv;
}

// ---------------------------------------------------------------------------
// Fully fused GINE MLP:  C = relu( relu((A + A2) @ W1 + b1) @ W2 + b2 )
// Tile 64 rows x all 128 cols; u (64x128) lives in LDS between the GEMMs.
// Us is [k][row] XOR-swizzled so col-major scalar writes avoid 16-way
// conflicts while phase-2 float4 reads stay 16B-aligned.
// In-place C == A is safe: each block reads only the rows it writes.
// ---------------------------------------------------------------------------
__global__ __launch_bounds__(256) void mlp_fused(
    const float* __restrict__ A, const float* __restrict__ A2,
    const float* __restrict__ W1, const float* __restrict__ b1,
    const float* __restrict__ W2, const float* __restrict__ b2,
    float* __restrict__ C)
{
    __shared__ float As[32][68];    // [k][row] 64 rows + pad
    __shared__ float Bs[32][132];   // [k][col]
    __shared__ float Us[128][64];   // [k(=col of u)][row], swizzled

    const int tid = threadIdx.x;
    const int m0 = blockIdx.x * 64;
    const int tx = tid & 15;        // 16 col groups x 8 cols
    const int ty = tid >> 4;        // 16 row groups x 4 rows
    const int r = ty * 4;
    const int c = tx * 8;

    const int lrow = tid >> 3;      // A loader: row within 32-row half
    const int lk4  = tid & 7;       // A loader: float4 index in k-chunk
    const int bc4  = tid & 31;      // B loader: col float4
    const int bk   = tid >> 5;      // B loader: k row

    float acc[4][8];
#pragma unroll
    for (int i = 0; i < 4; ++i)
#pragma unroll
        for (int j = 0; j < 8; ++j) acc[i][j] = 0.0f;

    // ---------------- phase 1: u = relu((A+A2) @ W1 + b1) ----------------
    for (int kc = 0; kc < DD; kc += 32) {
#pragma unroll
        for (int p = 0; p < 2; ++p) {
            int row = p * 32 + lrow;
            float4 v = *(const float4*)(A + (size_t)(m0 + row) * DD + kc + lk4 * 4);
            float4 v2 = *(const float4*)(A2 + (size_t)(m0 + row) * DD + kc + lk4 * 4);
            v.x += v2.x; v.y += v2.y; v.z += v2.z; v.w += v2.w;
            As[lk4 * 4 + 0][row] = v.x;
            As[lk4 * 4 + 1][row] = v.y;
            As[lk4 * 4 + 2][row] = v.z;
            As[lk4 * 4 + 3][row] = v.w;
        }
#pragma unroll
        for (int p = 0; p < 4; ++p) {
            int kk = p * 8 + bk;
            *(float4*)&Bs[kk][bc4 * 4] =
                *(const float4*)(W1 + (size_t)(kc + kk) * DD + bc4 * 4);
        }
        __syncthreads();
#pragma unroll
        for (int k = 0; k < 32; ++k) {
            float4 a0 = *(const float4*)&As[k][r];
            float4 b0 = *(const float4*)&Bs[k][c];
            float4 b1v = *(const float4*)&Bs[k][c + 4];
            float av[4] = {a0.x, a0.y, a0.z, a0.w};
            float bv[8] = {b0.x, b0.y, b0.z, b0.w, b1v.x, b1v.y, b1v.z, b1v.w};
#pragma unroll
            for (int i = 0; i < 4; ++i)
#pragma unroll
                for (int j = 0; j < 8; ++j)
                    acc[i][j] = fmaf(av[i], bv[j], acc[i][j]);
        }
        __syncthreads();
    }

    // u -> LDS (swizzled), then reset accumulators
    {
        float4 bb0 = *(const float4*)(b1 + c);
        float4 bb1 = *(const float4*)(b1 + c + 4);
        float bv[8] = {bb0.x, bb0.y, bb0.z, bb0.w, bb1.x, bb1.y, bb1.z, bb1.w};
#pragma unroll
        for (int j = 0; j < 8; ++j) {
            int col = c + j;
            int sw = ((col >> 3) & 7) << 2;
#pragma unroll
            for (int i = 0; i < 4; ++i) {
                float u = fmaxf(acc[i][j] + bv[j], 0.0f);
                Us[col][(r + i) ^ sw] = u;
                acc[i][j] = 0.0f;    // reuse for phase 2 (overwritten per j; ok)
            }
        }
    }
#pragma unroll
    for (int i = 0; i < 4; ++i)
#pragma unroll
        for (int j = 0; j < 8; ++j) acc[i][j] = 0.0f;

    // ---------------- phase 2: C = relu(u @ W2 + b2) ----------------
    for (int kc = 0; kc < DD; kc += 32) {
#pragma unroll
        for (int p = 0; p < 4; ++p) {
            int kk = p * 8 + bk;
            *(float4*)&Bs[kk][bc4 * 4] =
                *(const float4*)(W2 + (size_t)(kc + kk) * DD + bc4 * 4);
        }
        __syncthreads();   // also orders Us writes before Us reads (kc==0)
#pragma unroll
        for (int k2 = 0; k2 < 32; ++k2) {
            int k = kc + k2;
            float4 a0 = *(const float4*)&Us[k][r ^ (((k >> 3) & 7) << 2)];
            float4 b0 = *(const float4*)&Bs[k2][c];
            float4 b1v = *(const float4*)&Bs[k2][c + 4];
            float av[4] = {a0.x, a0.y, a0.z, a0.w};
            float bv[8] = {b0.x, b0.y, b0.z, b0.w, b1v.x, b1v.y, b1v.z, b1v.w};
#pragma unroll
            for (int i = 0; i < 4; ++i)
#pragma unroll
                for (int j = 0; j < 8; ++j)
                    acc[i][j] = fmaf(av[i], bv[j], acc[i][j]);
        }
        __syncthreads();
    }

    float4 bb0 = *(const float4*)(b2 + c);
    float4 bb1 = *(const float4*)(b2 + c + 4);
    float bv[8] = {bb0.x, bb0.y, bb0.z, bb0.w, bb1.x, bb1.y, bb1.z, bb1.w};
#pragma unroll
    for (int i = 0; i < 4; ++i) {
        int gr = m0 + r + i;
        float4 o0, o1;
        o0.x = fmaxf(acc[i][0] + bv[0], 0.0f);
        o0.y = fmaxf(acc[i][1] + bv[1], 0.0f);
        o0.z = fmaxf(acc[i][2] + bv[2], 0.0f);
        o0.w = fmaxf(acc[i][3] + bv[3], 0.0f);
        o1.x = fmaxf(acc[i][4] + bv[4], 0.0f);
        o1.y = fmaxf(acc[i][5] + bv[5], 0.0f);
        o1.z = fmaxf(acc[i][6] + bv[6], 0.0f);
        o1.w = fmaxf(acc[i][7] + bv[7], 0.0f);
        *(float4*)(C + (size_t)gr * DD + c) = o0;
        *(float4*)(C + (size_t)gr * DD + c + 4) = o1;
    }
}

// ---------------------------------------------------------------------------
// Global mean pool (batch sorted -> register runs, flush on graph change)
// ---------------------------------------------------------------------------
__device__ inline void pool_flush(float* __restrict__ out, int g, int lane,
                                  const float4& acc)
{
    float* o = out + (size_t)g * DD + lane * 4;
    unsafeAtomicAdd(o + 0, acc.x);
    unsafeAtomicAdd(o + 1, acc.y);
    unsafeAtomicAdd(o + 2, acc.z);
    unsafeAtomicAdd(o + 3, acc.w);
}

__global__ __launch_bounds__(256) void pool_k(
    const float* __restrict__ h, const int* __restrict__ batch,
    float* __restrict__ out, int* __restrict__ cnt)
{
    int tid = blockIdx.x * 256 + threadIdx.x;
    int grp = tid >> 5;
    int lane = tid & 31;
    int n0 = grp * 16;
    if (n0 >= NN) return;
    int nend = min(n0 + 16, NN);

    float4 acc = make_float4(0.f, 0.f, 0.f, 0.f);
    int gprev = batch[n0];
    int crun = 0;
    for (int n = n0; n < nend; ++n) {
        int g = batch[n];
        if (g != gprev) {
            pool_flush(out, gprev, lane, acc);
            if (lane == 0) atomicAdd(cnt + gprev, crun);
            acc = make_float4(0.f, 0.f, 0.f, 0.f);
            crun = 0;
            gprev = g;
        }
        float4 v = *(const float4*)(h + (size_t)n * DD + lane * 4);
        acc.x += v.x; acc.y += v.y; acc.z += v.z; acc.w += v.w;
        ++crun;
    }
    pool_flush(out, gprev, lane, acc);
    if (lane == 0) atomicAdd(cnt + gprev, crun);
}

__global__ __launch_bounds__(256) void pool_div_k(float* __restrict__ out,
                                                  const int* __restrict__ cnt)
{
    int tid = blockIdx.x * 256 + threadIdx.x;
    if (tid >= NG * DD) return;
    int g = tid / DD;
    float c = fmaxf((float)cnt[g], 1.0f);
    out[tid] = out[tid] / c;
}

// ---------------------------------------------------------------------------
extern "C" void kernel_launch(void* const* d_in, const int* in_sizes, int n_in,
                              void* d_out, int out_size, void* d_ws, size_t ws_size,
                              hipStream_t stream)
{
    const float* x     = (const float*)d_in[0];
    const float* ea    = (const float*)d_in[1];
    const int*   ei    = (const int*)d_in[2];
    const int*   batch = (const int*)d_in[3];
    const float* w1[4], * b1[4], * w2[4], * b2[4];
    for (int l = 0; l < 4; ++l) {
        w1[l] = (const float*)d_in[4 + 4 * l];
        b1[l] = (const float*)d_in[5 + 4 * l];
        w2[l] = (const float*)d_in[6 + 4 * l];
        b2[l] = (const float*)d_in[7 + 4 * l];
    }

    const int* srcp = ei;            // edge_index[0]
    const int* dstp = ei + NE;       // edge_index[1]

    char* ws = (char*)d_ws;
    const size_t hbytes = (size_t)NN * DD * sizeof(float);   // 20.48 MB
    float* agg = (float*)ws;
    float* hA  = (float*)(ws + hbytes);
    char*  p   = ws + 2 * hbytes;
    int*  cnt_node = (int*)p;           p += ((NN * 4 + 255) & ~255);
    int*  row_ptr  = (int*)p;           p += (((NN + 1) * 4 + 255) & ~255);
    int*  cursor   = (int*)p;           p += ((NN * 4 + 255) & ~255);
    int2* elist    = (int2*)p;          p += (((size_t)NE * 8 + 255) & ~255);
    int*  cntG     = (int*)p;

    const int eblocks     = (NE + 255) / 256;   // 2500
    const int gblocks     = (NN + 7) / 8;       // 5000
    const int mlp_blocks  = NN / 64;            // 625
    const int pool_blocks = ((NN / 16) * 32 + 255) / 256;

    // ---- build CSR by dst (reused by all 4 layers)
    hipMemsetAsync(cnt_node, 0, NN * sizeof(int), stream);
    hist_k<<<eblocks, 256, 0, stream>>>(dstp, cnt_node);
    scan_k<<<1, 1024, 0, stream>>>(cnt_node, row_ptr, cursor);
    fill_k<<<eblocks, 256, 0, stream>>>(srcp, dstp, cursor, elist);

    // ---- 4 GINE layers (hA in-place from layer 2 on; block-safe)
    const float* hcur = x;
    for (int l = 0; l < 4; ++l) {
        gather_k<<<gblocks, 256, 0, stream>>>(hcur, ea, row_ptr, elist, agg);
        mlp_fused<<<mlp_blocks, 256, 0, stream>>>(hcur, agg, w1[l], b1[l],
                                                  w2[l], b2[l], hA);
        hcur = hA;
    }

    // ---- global mean pool
    hipMemsetAsync(d_out, 0, (size_t)NG * DD * sizeof(float), stream);
    hipMemsetAsync(cntG, 0, NG * sizeof(int), stream);
    pool_k<<<pool_blocks, 256, 0, stream>>>(hcur, batch, (float*)d_out, cntG);
    pool_div_k<<<(NG * DD + 255) / 256, 256, 0, stream>>>((float*)d_out, cntG);
}

// Round 4
// 1141.555 us; speedup vs baseline: 1.0710x; 1.0710x over previous
//
#include <hip/hip_runtime.h>

#define NN 40000      // nodes
#define NE 640000     // edges
#define DD 128        // feature dim
#define NG 64         // graphs

typedef float vf4 __attribute__((ext_vector_type(4)));
typedef unsigned short us4 __attribute__((ext_vector_type(4)));

__device__ inline unsigned short f2bf(float f) {        // round-nearest-even
    unsigned int u = __float_as_uint(f);
    return (unsigned short)((u + 0x7fffu + ((u >> 16) & 1u)) >> 16);
}
__device__ inline float bf2f(unsigned short s) {
    return __uint_as_float((unsigned int)s << 16);
}

// ---------------------------------------------------------------------------
// edge_attr fp32 -> bf16, once per launch (164 MB result fits in 256 MB L3)
// ---------------------------------------------------------------------------
__global__ __launch_bounds__(256) void cvt_k(const float* __restrict__ ea,
                                             unsigned short* __restrict__ eb)
{
    size_t i = ((size_t)blockIdx.x * 256 + threadIdx.x) * 8;  // exact cover
    vf4 a = __builtin_nontemporal_load((const vf4*)(ea + i));
    vf4 b = __builtin_nontemporal_load((const vf4*)(ea + i + 4));
    us4 o0 = {f2bf(a.x), f2bf(a.y), f2bf(a.z), f2bf(a.w)};
    us4 o1 = {f2bf(b.x), f2bf(b.y), f2bf(b.z), f2bf(b.w)};
    *(us4*)(eb + i) = o0;
    *(us4*)(eb + i + 4) = o1;
}

// ---------------------------------------------------------------------------
// CSR build (once per launch; edge_index constant across layers)
// ---------------------------------------------------------------------------
__global__ __launch_bounds__(256) void hist_k(const int* __restrict__ dst,
                                              int* __restrict__ cnt)
{
    int e = blockIdx.x * 256 + threadIdx.x;
    if (e < NE) atomicAdd(&cnt[dst[e]], 1);
}

// 3-phase scan: local sums (40/thread) -> one 1024 ladder -> local writeout
__global__ __launch_bounds__(1024) void scan_k(const int* __restrict__ cnt,
                                               int* __restrict__ row_ptr,
                                               int* __restrict__ cursor)
{
    __shared__ int sm[1024];
    int t = threadIdx.x;
    int base = t * 40;                       // 1024*40 = 40960 >= NN
    int s = 0;
#pragma unroll 8
    for (int i = 0; i < 40; ++i) {
        int idx = base + i;
        if (idx < NN) s += cnt[idx];
    }
    sm[t] = s;
    __syncthreads();
    for (int off = 1; off < 1024; off <<= 1) {
        int x = (t >= off) ? sm[t - off] : 0;
        __syncthreads();
        sm[t] += x;
        __syncthreads();
    }
    int run = sm[t] - s;                     // exclusive prefix
#pragma unroll 8
    for (int i = 0; i < 40; ++i) {
        int idx = base + i;
        if (idx < NN) {
            row_ptr[idx] = run;
            cursor[idx] = run;
            run += cnt[idx];
        }
    }
    if (t == 1023) row_ptr[NN] = run;        // == NE
}

__global__ __launch_bounds__(256) void fill_k(const int* __restrict__ src,
                                              const int* __restrict__ dst,
                                              int* __restrict__ cursor,
                                              int2* __restrict__ elist)
{
    int e = blockIdx.x * 256 + threadIdx.x;
    if (e < NE) {
        int d = dst[e];
        int pos = atomicAdd(&cursor[d], 1);
        elist[pos] = make_int2(src[e], e);
    }
}

// ---------------------------------------------------------------------------
// Atomic-free aggregation, bf16 edge_attr, 4-edge unroll (8 loads in flight
// per lane).  agg[n] = sum_e relu(h[src_e] + ea[eid_e]).
// ---------------------------------------------------------------------------
__device__ inline void acc1(float4& acc, const float* __restrict__ h,
                            const unsigned short* __restrict__ eb,
                            int s, int id, int lane)
{
    const float4 xv = *(const float4*)(h + (size_t)s * DD + lane * 4);
    us4 bv = *(const us4*)(eb + (size_t)id * DD + lane * 4);
    acc.x += fmaxf(xv.x + bf2f(bv.x), 0.f);
    acc.y += fmaxf(xv.y + bf2f(bv.y), 0.f);
    acc.z += fmaxf(xv.z + bf2f(bv.z), 0.f);
    acc.w += fmaxf(xv.w + bf2f(bv.w), 0.f);
}

__global__ __launch_bounds__(256) void gather_bf(
    const float* __restrict__ h, const unsigned short* __restrict__ eb,
    const int* __restrict__ row_ptr, const int2* __restrict__ elist,
    float* __restrict__ agg)
{
    int grp = blockIdx.x * 8 + (threadIdx.x >> 5);   // node id
    int lane = threadIdx.x & 31;
    if (grp >= NN) return;
    int beg = row_ptr[grp], end = row_ptr[grp + 1];

    float4 a0 = make_float4(0.f, 0.f, 0.f, 0.f);
    float4 a1 = make_float4(0.f, 0.f, 0.f, 0.f);
    float4 a2 = make_float4(0.f, 0.f, 0.f, 0.f);
    float4 a3 = make_float4(0.f, 0.f, 0.f, 0.f);
    int e = beg;
    for (; e + 4 <= end; e += 4) {
        int2 p0 = elist[e];
        int2 p1 = elist[e + 1];
        int2 p2 = elist[e + 2];
        int2 p3 = elist[e + 3];
        acc1(a0, h, eb, p0.x, p0.y, lane);
        acc1(a1, h, eb, p1.x, p1.y, lane);
        acc1(a2, h, eb, p2.x, p2.y, lane);
        acc1(a3, h, eb, p3.x, p3.y, lane);
    }
    for (; e < end; ++e) {
        int2 p0 = elist[e];
        acc1(a0, h, eb, p0.x, p0.y, lane);
    }
    float4 o;
    o.x = (a0.x + a1.x) + (a2.x + a3.x);
    o.y = (a0.y + a1.y) + (a2.y + a3.y);
    o.z = (a0.z + a1.z) + (a2.z + a3.z);
    o.w = (a0.w + a1.w) + (a2.w + a3.w);
    *(float4*)(agg + (size_t)grp * DD + lane * 4) = o;
}

// fp32 fallback (used only if ws_size can't hold the bf16 edge cache)
__device__ inline void acc1f(float4& acc, const float* __restrict__ h,
                             const float* __restrict__ ea,
                             int s, int id, int lane)
{
    const float4 xv = *(const float4*)(h + (size_t)s * DD + lane * 4);
    vf4 ev = __builtin_nontemporal_load((const vf4*)(ea + (size_t)id * DD + lane * 4));
    acc.x += fmaxf(xv.x + ev.x, 0.f);
    acc.y += fmaxf(xv.y + ev.y, 0.f);
    acc.z += fmaxf(xv.z + ev.z, 0.f);
    acc.w += fmaxf(xv.w + ev.w, 0.f);
}

__global__ __launch_bounds__(256) void gather_f32(
    const float* __restrict__ h, const float* __restrict__ ea,
    const int* __restrict__ row_ptr, const int2* __restrict__ elist,
    float* __restrict__ agg)
{
    int grp = blockIdx.x * 8 + (threadIdx.x >> 5);
    int lane = threadIdx.x & 31;
    if (grp >= NN) return;
    int beg = row_ptr[grp], end = row_ptr[grp + 1];

    float4 a0 = make_float4(0.f, 0.f, 0.f, 0.f);
    float4 a1 = make_float4(0.f, 0.f, 0.f, 0.f);
    float4 a2 = make_float4(0.f, 0.f, 0.f, 0.f);
    float4 a3 = make_float4(0.f, 0.f, 0.f, 0.f);
    int e = beg;
    for (; e + 4 <= end; e += 4) {
        int2 p0 = elist[e];
        int2 p1 = elist[e + 1];
        int2 p2 = elist[e + 2];
        int2 p3 = elist[e + 3];
        acc1f(a0, h, ea, p0.x, p0.y, lane);
        acc1f(a1, h, ea, p1.x, p1.y, lane);
        acc1f(a2, h, ea, p2.x, p2.y, lane);
        acc1f(a3, h, ea, p3.x, p3.y, lane);
    }
    for (; e < end; ++e) {
        int2 p0 = elist[e];
        acc1f(a0, h, ea, p0.x, p0.y, lane);
    }
    float4 o;
    o.x = (a0.x + a1.x) + (a2.x + a3.x);
    o.y = (a0.y + a1.y) + (a2.y + a3.y);
    o.z = (a0.z + a1.z) + (a2.z + a3.z);
    o.w = (a0.w + a1.w) + (a2.w + a3.w);
    *(float4*)(agg + (size_t)grp * DD + lane * 4) = o;
}

// ---------------------------------------------------------------------------
// Fused GEMM + bias + ReLU:  C = relu((A [+ A2]) @ W + bias)
// M = 40000, N = K = 128.  Tile 64x128, 256 thr, 4x8/thread.  25.4 KB LDS ->
// 6 blocks/CU (R3 showed a fatter fused kernel loses on occupancy).
// ---------------------------------------------------------------------------
template <int FUSE>
__global__ __launch_bounds__(256) void mlp_gemm(
    const float* __restrict__ A, const float* __restrict__ A2,
    const float* __restrict__ W, const float* __restrict__ bias,
    float* __restrict__ C)
{
    __shared__ float As[32][68];    // [k][row], 64 rows + pad
    __shared__ float Bs[32][132];   // [k][col]

    const int tid = threadIdx.x;
    const int m0 = blockIdx.x * 64;
    const int tx = tid & 15;
    const int ty = tid >> 4;
    const int r = ty * 4;
    const int c = tx * 8;

    float acc[4][8];
#pragma unroll
    for (int i = 0; i < 4; ++i)
#pragma unroll
        for (int j = 0; j < 8; ++j) acc[i][j] = 0.0f;

    const int lrow = tid >> 3;
    const int lk4  = tid & 7;
    const int bc4  = tid & 31;
    const int bk   = tid >> 5;

    for (int kc = 0; kc < DD; kc += 32) {
#pragma unroll
        for (int p = 0; p < 2; ++p) {
            int row = p * 32 + lrow;
            float4 v = *(const float4*)(A + (size_t)(m0 + row) * DD + kc + lk4 * 4);
            if (FUSE) {
                float4 v2 = *(const float4*)(A2 + (size_t)(m0 + row) * DD + kc + lk4 * 4);
                v.x += v2.x; v.y += v2.y; v.z += v2.z; v.w += v2.w;
            }
            As[lk4 * 4 + 0][row] = v.x;
            As[lk4 * 4 + 1][row] = v.y;
            As[lk4 * 4 + 2][row] = v.z;
            As[lk4 * 4 + 3][row] = v.w;
        }
#pragma unroll
        for (int p = 0; p < 4; ++p) {
            int kk = p * 8 + bk;
            *(float4*)&Bs[kk][bc4 * 4] =
                *(const float4*)(W + (size_t)(kc + kk) * DD + bc4 * 4);
        }
        __syncthreads();

#pragma unroll
        for (int k = 0; k < 32; ++k) {
            float4 av4 = *(const float4*)&As[k][r];
            float4 b0 = *(const float4*)&Bs[k][c];
            float4 b1 = *(const float4*)&Bs[k][c + 4];
            float av[4] = {av4.x, av4.y, av4.z, av4.w};
            float bv[8] = {b0.x, b0.y, b0.z, b0.w, b1.x, b1.y, b1.z, b1.w};
#pragma unroll
            for (int i = 0; i < 4; ++i)
#pragma unroll
                for (int j = 0; j < 8; ++j)
                    acc[i][j] = fmaf(av[i], bv[j], acc[i][j]);
        }
        __syncthreads();
    }

    float4 bb0 = *(const float4*)(bias + c);
    float4 bb1 = *(const float4*)(bias + c + 4);
    float bv[8] = {bb0.x, bb0.y, bb0.z, bb0.w, bb1.x, bb1.y, bb1.z, bb1.w};
#pragma unroll
    for (int i = 0; i < 4; ++i) {
        int gr = m0 + r + i;
        float4 o0, o1;
        o0.x = fmaxf(acc[i][0] + bv[0], 0.0f);
        o0.y = fmaxf(acc[i][1] + bv[1], 0.0f);
        o0.z = fmaxf(acc[i][2] + bv[2], 0.0f);
        o0.w = fmaxf(acc[i][3] + bv[3], 0.0f);
        o1.x = fmaxf(acc[i][4] + bv[4], 0.0f);
        o1.y = fmaxf(acc[i][5] + bv[5], 0.0f);
        o1.z = fmaxf(acc[i][6] + bv[6], 0.0f);
        o1.w = fmaxf(acc[i][7] + bv[7], 0.0f);
        *(float4*)(C + (size_t)gr * DD + c) = o0;
        *(float4*)(C + (size_t)gr * DD + c + 4) = o1;
    }
}

// ---------------------------------------------------------------------------
// Global mean pool (batch sorted -> register runs, flush on graph change)
// ---------------------------------------------------------------------------
__device__ inline void pool_flush(float* __restrict__ out, int g, int lane,
                                  const float4& acc)
{
    float* o = out + (size_t)g * DD + lane * 4;
    unsafeAtomicAdd(o + 0, acc.x);
    unsafeAtomicAdd(o + 1, acc.y);
    unsafeAtomicAdd(o + 2, acc.z);
    unsafeAtomicAdd(o + 3, acc.w);
}

__global__ __launch_bounds__(256) void pool_k(
    const float* __restrict__ h, const int* __restrict__ batch,
    float* __restrict__ out, int* __restrict__ cnt)
{
    int tid = blockIdx.x * 256 + threadIdx.x;
    int grp = tid >> 5;
    int lane = tid & 31;
    int n0 = grp * 16;
    if (n0 >= NN) return;
    int nend = min(n0 + 16, NN);

    float4 acc = make_float4(0.f, 0.f, 0.f, 0.f);
    int gprev = batch[n0];
    int crun = 0;
    for (int n = n0; n < nend; ++n) {
        int g = batch[n];
        if (g != gprev) {
            pool_flush(out, gprev, lane, acc);
            if (lane == 0) atomicAdd(cnt + gprev, crun);
            acc = make_float4(0.f, 0.f, 0.f, 0.f);
            crun = 0;
            gprev = g;
        }
        float4 v = *(const float4*)(h + (size_t)n * DD + lane * 4);
        acc.x += v.x; acc.y += v.y; acc.z += v.z; acc.w += v.w;
        ++crun;
    }
    pool_flush(out, gprev, lane, acc);
    if (lane == 0) atomicAdd(cnt + gprev, crun);
}

__global__ __launch_bounds__(256) void pool_div_k(float* __restrict__ out,
                                                  const int* __restrict__ cnt)
{
    int tid = blockIdx.x * 256 + threadIdx.x;
    if (tid >= NG * DD) return;
    int g = tid / DD;
    float c = fmaxf((float)cnt[g], 1.0f);
    out[tid] = out[tid] / c;
}

// ---------------------------------------------------------------------------
extern "C" void kernel_launch(void* const* d_in, const int* in_sizes, int n_in,
                              void* d_out, int out_size, void* d_ws, size_t ws_size,
                              hipStream_t stream)
{
    const float* x     = (const float*)d_in[0];
    const float* ea    = (const float*)d_in[1];
    const int*   ei    = (const int*)d_in[2];
    const int*   batch = (const int*)d_in[3];
    const float* w1[4], * b1[4], * w2[4], * b2[4];
    for (int l = 0; l < 4; ++l) {
        w1[l] = (const float*)d_in[4 + 4 * l];
        b1[l] = (const float*)d_in[5 + 4 * l];
        w2[l] = (const float*)d_in[6 + 4 * l];
        b2[l] = (const float*)d_in[7 + 4 * l];
    }

    const int* srcp = ei;            // edge_index[0]
    const int* dstp = ei + NE;       // edge_index[1]

    char* ws = (char*)d_ws;
    const size_t hbytes = (size_t)NN * DD * sizeof(float);   // 20.48 MB
    float* agg = (float*)ws;
    float* hA  = (float*)(ws + hbytes);
    char*  p   = ws + 2 * hbytes;
    int*  cnt_node = (int*)p;           p += ((NN * 4 + 255) & ~255);
    int*  row_ptr  = (int*)p;           p += (((NN + 1) * 4 + 255) & ~255);
    int*  cursor   = (int*)p;           p += ((NN * 4 + 255) & ~255);
    int2* elist    = (int2*)p;          p += (((size_t)NE * 8 + 255) & ~255);
    int*  cntG     = (int*)p;           p += 256;
    unsigned short* ea_bf = (unsigned short*)p;
    const size_t need_bf = (size_t)(p - ws) + (size_t)NE * DD * 2;
    const bool use_bf = (ws_size >= need_bf);   // ws_size is call-invariant

    const int eblocks     = (NE + 255) / 256;   // 2500
    const int gblocks     = (NN + 7) / 8;       // 5000
    const int gemm_blocks = NN / 64;            // 625
    const int pool_blocks = ((NN / 16) * 32 + 255) / 256;

    // ---- one-time per launch: bf16 edge cache + CSR by dst
    if (use_bf)
        cvt_k<<<(NE * DD / 8 + 255) / 256, 256, 0, stream>>>(ea, ea_bf);
    hipMemsetAsync(cnt_node, 0, NN * sizeof(int), stream);
    hist_k<<<eblocks, 256, 0, stream>>>(dstp, cnt_node);
    scan_k<<<1, 1024, 0, stream>>>(cnt_node, row_ptr, cursor);
    fill_k<<<eblocks, 256, 0, stream>>>(srcp, dstp, cursor, elist);

    // ---- 4 GINE layers
    const float* hcur = x;
    for (int l = 0; l < 4; ++l) {
        if (use_bf)
            gather_bf<<<gblocks, 256, 0, stream>>>(hcur, ea_bf, row_ptr, elist, agg);
        else
            gather_f32<<<gblocks, 256, 0, stream>>>(hcur, ea, row_ptr, elist, agg);
        // u = relu((hcur + agg) @ W1 + b1), in place over agg (block-safe)
        mlp_gemm<1><<<gemm_blocks, 256, 0, stream>>>(hcur, agg, w1[l], b1[l], agg);
        // hnext = relu(u @ W2 + b2)
        mlp_gemm<0><<<gemm_blocks, 256, 0, stream>>>(agg, nullptr, w2[l], b2[l], hA);
        hcur = hA;
    }

    // ---- global mean pool
    hipMemsetAsync(d_out, 0, (size_t)NG * DD * sizeof(float), stream);
    hipMemsetAsync(cntG, 0, NG * sizeof(int), stream);
    pool_k<<<pool_blocks, 256, 0, stream>>>(hcur, batch, (float*)d_out, cntG);
    pool_div_k<<<(NG * DD + 255) / 256, 256, 0, stream>>>((float*)d_out, cntG);
}